// Round 5
// baseline (209.154 us; speedup 1.0000x reference)
//
#include <hip/hip_runtime.h>
#include <hip/hip_bf16.h>
#include <stdint.h>

#define B_   8
#define L_   2048
#define D_   256
#define H_   256
#define TJ   64          // j-tile
#define NT   (L_/TJ)     // 32 tiles
#define BM   128         // rows per block

typedef short bf16x8 __attribute__((ext_vector_type(8)));
typedef float f32x4  __attribute__((ext_vector_type(4)));

#define MFMA(a,b,c) __builtin_amdgcn_mfma_f32_16x16x32_bf16(a,b,c,0,0,0)

typedef unsigned int u32;
__device__ __forceinline__ void gload_lds16(const void* g, void* l){
  __builtin_amdgcn_global_load_lds((const __attribute__((address_space(1))) u32*)g,
                                   (__attribute__((address_space(3))) u32*)l, 16, 0, 0);
}

__device__ __forceinline__ unsigned short f2bf(float f){
  __hip_bfloat16 h = __float2bfloat16(f);
  unsigned short us;
  __builtin_memcpy(&us, &h, 2);
  return us;
}

// ---------------- weight norm (both sets in one launch; y selects a/b)
__global__ __launch_bounds__(256) void wnorm_kernel(const float* __restrict__ av,
      const float* __restrict__ ag, const float* __restrict__ bv,
      const float* __restrict__ bg, unsigned short* __restrict__ wa,
      unsigned short* __restrict__ wb){
  int sel = blockIdx.y;
  const float* v = sel ? bv : av;
  const float* g = sel ? bg : ag;
  unsigned short* w = sel ? wb : wa;
  int h = blockIdx.x;
  int d = threadIdx.x;
  float x = v[h*D_ + d];
  float sq = x*x;
  for (int off = 32; off; off >>= 1) sq += __shfl_down(sq, off, 64);
  __shared__ float red[4];
  int lane = threadIdx.x & 63, wid = threadIdx.x >> 6;
  if (lane == 0) red[wid] = sq;
  __syncthreads();
  float tot = red[0] + red[1] + red[2] + red[3];
  float scale = g[h] / sqrtf(tot);
  w[h*D_ + d] = f2bf(x * scale);
}

// ---------------- transpose+convert both tensors: x [B][L][D] f32 -> xT [B][D][L] bf16
__global__ __launch_bounds__(256) void transpose_kernel(const float* __restrict__ a,
      const float* __restrict__ b, unsigned short* __restrict__ aT,
      unsigned short* __restrict__ bT){
  __shared__ float tile[32][33];
  int sel = blockIdx.z >> 3;
  int bz  = blockIdx.z & 7;
  const float* x = sel ? b : a;
  unsigned short* xT = sel ? bT : aT;
  int l0 = blockIdx.x * 32;
  int d0 = blockIdx.y * 32;
  int tx = threadIdx.x, ty = threadIdx.y; // (32,8)
  const float* xp = x + (size_t)bz * L_ * D_;
  for (int k = 0; k < 4; k++)
    tile[ty + 8*k][tx] = xp[(size_t)(l0 + ty + 8*k) * D_ + d0 + tx];
  __syncthreads();
  unsigned short* op = xT + (size_t)bz * D_ * L_;
  for (int k = 0; k < 4; k++)
    op[(size_t)(d0 + ty + 8*k) * L_ + l0 + tx] = f2bf(tile[tx][ty + 8*k]);
}

// ---------------- hx = bf16(scale * relu(x @ w^T + bias)); all 256 cols per block
__global__ __launch_bounds__(256) void hgemm_kernel(const float* __restrict__ a,
      const float* __restrict__ b, const unsigned short* __restrict__ wa,
      const unsigned short* __restrict__ wb, const float* __restrict__ a_bias,
      const float* __restrict__ b_bias, const float* __restrict__ tau_ptr,
      unsigned short* __restrict__ ha, unsigned short* __restrict__ hb){
  int sel = blockIdx.y;
  const float* x = sel ? b : a;
  const unsigned short* w = sel ? wb : wa;
  const float* bias = sel ? b_bias : a_bias;
  unsigned short* hx = sel ? hb : ha;
  float scale = sel ? 1.0f : tau_ptr[0];
  int m0 = blockIdx.x * 64;
  int lane = threadIdx.x & 63, wid = threadIdx.x >> 6;
  int p = lane & 15, q = lane >> 4;
  int row = m0 + wid*16 + p;
  f32x4 acc[16] = {};
  for (int kk = 0; kk < 8; kk++){
    const float* ap = x + (size_t)row * 256 + kk*32 + q*8;
    f32x4 a0 = *(const f32x4*)ap;
    f32x4 a1 = *(const f32x4*)(ap + 4);
    bf16x8 af;
    af[0]=(short)f2bf(a0[0]); af[1]=(short)f2bf(a0[1]); af[2]=(short)f2bf(a0[2]); af[3]=(short)f2bf(a0[3]);
    af[4]=(short)f2bf(a1[0]); af[5]=(short)f2bf(a1[1]); af[6]=(short)f2bf(a1[2]); af[7]=(short)f2bf(a1[3]);
    #pragma unroll
    for (int n = 0; n < 16; n++){
      bf16x8 bfr = *(const bf16x8*)(w + (size_t)(n*16 + p) * 256 + kk*32 + q*8);
      acc[n] = MFMA(af, bfr, acc[n]);
    }
  }
  #pragma unroll
  for (int n = 0; n < 16; n++){
    float bv = bias[n*16 + p];
    #pragma unroll
    for (int r = 0; r < 4; r++){
      int orow = m0 + wid*16 + q*4 + r;
      float vv = acc[n][r] + bv;
      vv = vv > 0.f ? vv : 0.f;
      hx[(size_t)orow * 256 + n*16 + p] = f2bf(vv * scale);
    }
  }
}

// ---------------- fused flash alignment, LDS-staged + double-buffered.
// 8 waves = 4 row-groups (wr: 32 rows each, as 2x16 groups) x 2 col-halves (wc).
// Each LDS B/V fragment read feeds 2 MFMAs (register-blocked M).
// End merge: wc pairs combine (m,s,acc) via LDS (accbuf unioned over staging).
__global__ __launch_bounds__(512, 2) void flash_kernel(
    const unsigned short* __restrict__ ha, const unsigned short* __restrict__ hb,
    const unsigned short* __restrict__ aT, const unsigned short* __restrict__ bT,
    const int* __restrict__ mask_a, const int* __restrict__ mask_b,
    float* __restrict__ out)
{
  // smem layout: [ union(staging 128KB | accbuf 132096B) ][ wtile 20480B ][ stats 2048B ]
  __shared__ __align__(16) char smem[132096 + 20480 + 2048];
  unsigned short* HBT = (unsigned short*)smem;          // [2][64][256]
  unsigned short* VTL = HBT + 2*64*256;                 // [2][256][64]
  float*          ACCB = (float*)smem;                  // [4][32][258]
  unsigned short* WT  = (unsigned short*)(smem + 132096); // [8][32][40]
  float*          MST = (float*)(smem + 132096 + 20480);  // [8][32]
  float*          SST = MST + 256;                        // [8][32]

  const int bid = blockIdx.x;
  const int s   = bid & 15;             // stream id; XCD = bid%8
  const int dir = s >> 3;
  const int bz  = s & 7;
  const int i0  = (bid >> 4) * BM;
  const int tid = threadIdx.x;
  const int lane = tid & 63;
  const int wid  = tid >> 6;
  const int wr = wid >> 1, wc = wid & 1;
  const int p = lane & 15, q = lane >> 4;

  const unsigned short* hA = dir ? hb : ha;
  const unsigned short* hB = dir ? ha : hb;
  const unsigned short* vT = dir ? aT : bT;
  const int* mask = dir ? mask_a : mask_b;
  float* outp = out + ((size_t)dir * B_ + bz) * L_ * D_;

  const unsigned short* hAp = hA + (size_t)bz * L_ * H_;
  const unsigned short* hBp = hB + (size_t)bz * L_ * H_;
  const unsigned short* vTp = vT + (size_t)bz * D_ * L_;
  const int* mp = mask + bz * L_;

  // staging source geometry
  const int hb_r0 = wid*2 + (lane >> 5);      // + k*16
  const int hb_s  = lane & 31;
  const int vt_r0 = wid*8 + (lane >> 3);      // + k*64
  const int vt_s  = lane & 7;

  // A fragments: two 16-row groups of this wave's 32 rows
  bf16x8 af[2][8];
  #pragma unroll
  for (int g = 0; g < 2; ++g)
    #pragma unroll
    for (int kk = 0; kk < 8; ++kk)
      af[g][kk] = *(const bf16x8*)(hAp + (size_t)(i0 + wr*32 + g*16 + p) * H_ + kk*32 + q*8);

  f32x4 acc[2][16];
  #pragma unroll
  for (int g = 0; g < 2; ++g)
    #pragma unroll
    for (int n = 0; n < 16; ++n) acc[g][n] = (f32x4){0.f,0.f,0.f,0.f};
  float m_run[2][4], s_run[2][4];
  #pragma unroll
  for (int g = 0; g < 2; ++g)
    #pragma unroll
    for (int r = 0; r < 4; ++r){ m_run[g][r] = -1e30f; s_run[g][r] = 0.f; }

  #define STAGE(bb, jj0) do {                                                     \
    _Pragma("unroll")                                                             \
    for (int k = 0; k < 4; ++k){                                                  \
      int rr = k*16 + hb_r0;                                                      \
      int sp = hb_s ^ (rr & 7);                                                   \
      gload_lds16(hBp + (size_t)((jj0) + rr) * H_ + sp*8,                         \
                  HBT + (bb)*16384 + (k*8192 + wid*1024)/2);                      \
    }                                                                             \
    _Pragma("unroll")                                                             \
    for (int k = 0; k < 4; ++k){                                                  \
      int rr = k*64 + vt_r0;                                                      \
      int sp = vt_s ^ (rr & 7);                                                   \
      gload_lds16(vTp + (size_t)rr * L_ + (jj0) + sp*8,                           \
                  VTL + (bb)*16384 + (k*8192 + wid*1024)/2);                      \
    }                                                                             \
  } while(0)

  STAGE(0, 0);
  __syncthreads();

  for (int jt = 0; jt < NT; ++jt){
    const int j0 = jt * TJ;
    const int cur = jt & 1;
    if (jt + 1 < NT) STAGE(cur ^ 1, j0 + TJ);

    // mask terms for this wave's 2 col-groups (cols wc*32 + cg*16 + p)
    float mm[2];
    #pragma unroll
    for (int cg = 0; cg < 2; ++cg)
      mm[cg] = (mp[j0 + wc*32 + cg*16 + p] > 0) ? 0.f : -1e9f;

    // ---- QK: P[32 rows][32 cols] for this wave
    f32x4 accp[2][2];
    #pragma unroll
    for (int g = 0; g < 2; ++g)
      #pragma unroll
      for (int cg = 0; cg < 2; ++cg) accp[g][cg] = (f32x4){0.f,0.f,0.f,0.f};
    __builtin_amdgcn_s_setprio(1);
    #pragma unroll
    for (int kk = 0; kk < 8; ++kk){
      int r0 = wc*32 + p;
      int r1 = wc*32 + 16 + p;
      bf16x8 b0 = *(const bf16x8*)(HBT + cur*16384 + r0*256 + (((kk*4+q) ^ (p & 7)))*8);
      bf16x8 b1 = *(const bf16x8*)(HBT + cur*16384 + r1*256 + (((kk*4+q) ^ (p & 7)))*8);
      accp[0][0] = MFMA(af[0][kk], b0, accp[0][0]);
      accp[1][0] = MFMA(af[1][kk], b0, accp[1][0]);
      accp[0][1] = MFMA(af[0][kk], b1, accp[0][1]);
      accp[1][1] = MFMA(af[1][kk], b1, accp[1][1]);
    }
    __builtin_amdgcn_s_setprio(0);

    // ---- mask + tile max
    float tmax[2][4];
    #pragma unroll
    for (int g = 0; g < 2; ++g)
      #pragma unroll
      for (int r = 0; r < 4; ++r){
        accp[g][0][r] += mm[0];
        accp[g][1][r] += mm[1];
        tmax[g][r] = fmaxf(accp[g][0][r], accp[g][1][r]);
      }
    #pragma unroll
    for (int off = 1; off < 16; off <<= 1)
      #pragma unroll
      for (int g = 0; g < 2; ++g)
        #pragma unroll
        for (int r = 0; r < 4; ++r)
          tmax[g][r] = fmaxf(tmax[g][r], __shfl_xor(tmax[g][r], off, 64));

    // ---- online update with defer-rescale (THR = 8)
    int need = 0;
    #pragma unroll
    for (int g = 0; g < 2; ++g)
      #pragma unroll
      for (int r = 0; r < 4; ++r)
        need |= (tmax[g][r] > m_run[g][r] + 8.f) ? 1 : 0;
    if (__any(need)){
      float fsc[2][4];
      #pragma unroll
      for (int g = 0; g < 2; ++g)
        #pragma unroll
        for (int r = 0; r < 4; ++r){
          float mn = fmaxf(m_run[g][r], tmax[g][r]);
          fsc[g][r] = __expf(m_run[g][r] - mn);
          s_run[g][r] *= fsc[g][r];
          m_run[g][r] = mn;
        }
      #pragma unroll
      for (int g = 0; g < 2; ++g)
        #pragma unroll
        for (int n = 0; n < 16; ++n)
          #pragma unroll
          for (int r = 0; r < 4; ++r)
            acc[g][n][r] *= fsc[g][r];
    }

    // ---- weights -> bf16 -> per-wave wtile (rows 32, stride 40)
    #pragma unroll
    for (int g = 0; g < 2; ++g)
      #pragma unroll
      for (int cg = 0; cg < 2; ++cg)
        #pragma unroll
        for (int r = 0; r < 4; ++r){
          float w = __expf(accp[g][cg][r] - m_run[g][r]);
          s_run[g][r] += w;
          WT[wid*1280 + (g*16 + q*4 + r)*40 + cg*16 + p] = f2bf(w);
        }
    asm volatile("s_waitcnt lgkmcnt(0)" ::: "memory");
    bf16x8 wf0 = *(const bf16x8*)(WT + wid*1280 + p*40 + q*8);
    bf16x8 wf1 = *(const bf16x8*)(WT + wid*1280 + (16 + p)*40 + q*8);

    // ---- PV: acc += W @ V (K=32 = this wave's col-half)
    __builtin_amdgcn_s_setprio(1);
    #pragma unroll
    for (int n = 0; n < 16; ++n){
      int sp = (wc*4 + q) ^ (p & 7);
      bf16x8 vf = *(const bf16x8*)(VTL + cur*16384 + (n*16 + p)*64 + sp*8);
      acc[0][n] = MFMA(wf0, vf, acc[0][n]);
      acc[1][n] = MFMA(wf1, vf, acc[1][n]);
    }
    __builtin_amdgcn_s_setprio(0);

    __syncthreads();
  }
  #undef STAGE

  // ---- reduce s over the 16 col-lanes
  #pragma unroll
  for (int off = 1; off < 16; off <<= 1)
    #pragma unroll
    for (int g = 0; g < 2; ++g)
      #pragma unroll
      for (int r = 0; r < 4; ++r)
        s_run[g][r] += __shfl_xor(s_run[g][r], off, 64);

  // ---- cross-wave (wc pair) merge
  if (p == 0){
    #pragma unroll
    for (int g = 0; g < 2; ++g)
      #pragma unroll
      for (int r = 0; r < 4; ++r){
        MST[wid*32 + g*16 + q*4 + r] = m_run[g][r];
        SST[wid*32 + g*16 + q*4 + r] = s_run[g][r];
      }
  }
  __syncthreads();
  float fac[2][4], invS[2][4];
  #pragma unroll
  for (int g = 0; g < 2; ++g)
    #pragma unroll
    for (int r = 0; r < 4; ++r){
      int row = g*16 + q*4 + r;
      float mo = MST[(wid^1)*32 + row], so = SST[(wid^1)*32 + row];
      float M = fmaxf(m_run[g][r], mo);
      fac[g][r] = __expf(m_run[g][r] - M);
      float S = s_run[g][r] * fac[g][r] + so * __expf(mo - M);
      invS[g][r] = 1.0f / S;
    }
  if (wc == 1){
    #pragma unroll
    for (int g = 0; g < 2; ++g)
      #pragma unroll
      for (int n = 0; n < 16; ++n)
        #pragma unroll
        for (int r = 0; r < 4; ++r)
          ACCB[wr*8256 + (g*16 + q*4 + r)*258 + n*16 + p] = acc[g][n][r] * fac[g][r];
  }
  __syncthreads();
  if (wc == 0){
    #pragma unroll
    for (int g = 0; g < 2; ++g)
      #pragma unroll
      for (int n = 0; n < 16; ++n)
        #pragma unroll
        for (int r = 0; r < 4; ++r){
          int row = g*16 + q*4 + r;
          outp[(size_t)(i0 + wr*32 + row) * D_ + n*16 + p] =
              (acc[g][n][r] * fac[g][r] + ACCB[wr*8256 + row*258 + n*16 + p]) * invS[g][r];
        }
  }
}

extern "C" void kernel_launch(void* const* d_in, const int* in_sizes, int n_in,
                              void* d_out, int out_size, void* d_ws, size_t ws_size,
                              hipStream_t stream) {
  const float* a      = (const float*)d_in[0];
  const float* b      = (const float*)d_in[1];
  const int*   mask_a = (const int*)d_in[2];
  const int*   mask_b = (const int*)d_in[3];
  const float* a_v    = (const float*)d_in[4];
  const float* a_g    = (const float*)d_in[5];
  const float* a_bias = (const float*)d_in[6];
  const float* b_v    = (const float*)d_in[7];
  const float* b_g    = (const float*)d_in[8];
  const float* b_bias = (const float*)d_in[9];
  const float* tau    = (const float*)d_in[10];

  float* out = (float*)d_out;

  char* ws = (char*)d_ws;
  const size_t SZ_W  = (size_t)H_ * D_ * 2;        // 128 KB
  const size_t SZ_H  = (size_t)B_ * L_ * H_ * 2;   // 8 MB
  unsigned short* wa = (unsigned short*)(ws);
  unsigned short* wb = (unsigned short*)(ws + SZ_W);
  unsigned short* ha = (unsigned short*)(ws + 2*SZ_W);
  unsigned short* hb = (unsigned short*)(ws + 2*SZ_W + SZ_H);
  unsigned short* aT = (unsigned short*)(ws + 2*SZ_W + 2*SZ_H);
  unsigned short* bT = (unsigned short*)(ws + 2*SZ_W + 3*SZ_H);
  size_t need = 2*SZ_W + 4*SZ_H;
  if (ws_size < need) return;

  // 1. normalized weights (both, one launch)
  wnorm_kernel<<<dim3(H_, 2), 256, 0, stream>>>(a_v, a_g, b_v, b_g, wa, wb);

  // 2. transposed bf16 copies of a and b ([B][D][L], one launch)
  {
    dim3 g(L_/32, D_/32, 16), blk(32, 8);
    transpose_kernel<<<g, blk, 0, stream>>>(a, b, aT, bT);
  }

  // 3. ha = bf16(tau*relu(a@wa^T + bias)), hb = bf16(relu(b@wb^T + bias)) (one launch)
  {
    dim3 g((B_*L_)/64, 2);
    hgemm_kernel<<<g, 256, 0, stream>>>(a, b, wa, wb, a_bias, b_bias, tau, ha, hb);
  }

  // 4. fused flash alignment, both directions (256 blocks = 1/CU, XCD-affine)
  {
    flash_kernel<<<dim3((L_/BM) * B_ * 2), 512, 0, stream>>>(
        ha, hb, aT, bT, mask_a, mask_b, out);
  }
}

// Round 6
// 178.969 us; speedup vs baseline: 1.1687x; 1.1687x over previous
//
#include <hip/hip_runtime.h>
#include <hip/hip_bf16.h>
#include <stdint.h>

#define B_   8
#define L_   2048
#define D_   256
#define H_   256
#define TJ   64          // j-tile
#define NT   (L_/TJ)     // 32 tiles
#define BM   128         // rows per block

typedef short bf16x8 __attribute__((ext_vector_type(8)));
typedef float f32x4  __attribute__((ext_vector_type(4)));

#define MFMA(a,b,c) __builtin_amdgcn_mfma_f32_16x16x32_bf16(a,b,c,0,0,0)

typedef unsigned int u32;
__device__ __forceinline__ void gload_lds16(const void* g, void* l){
  __builtin_amdgcn_global_load_lds((const __attribute__((address_space(1))) u32*)g,
                                   (__attribute__((address_space(3))) u32*)l, 16, 0, 0);
}

__device__ __forceinline__ unsigned short f2bf(float f){
  __hip_bfloat16 h = __float2bfloat16(f);
  unsigned short us;
  __builtin_memcpy(&us, &h, 2);
  return us;
}

// ---------------- weight norm (both sets in one launch; y selects a/b)
__global__ __launch_bounds__(256) void wnorm_kernel(const float* __restrict__ av,
      const float* __restrict__ ag, const float* __restrict__ bv,
      const float* __restrict__ bg, unsigned short* __restrict__ wa,
      unsigned short* __restrict__ wb){
  int sel = blockIdx.y;
  const float* v = sel ? bv : av;
  const float* g = sel ? bg : ag;
  unsigned short* w = sel ? wb : wa;
  int h = blockIdx.x;
  int d = threadIdx.x;
  float x = v[h*D_ + d];
  float sq = x*x;
  for (int off = 32; off; off >>= 1) sq += __shfl_down(sq, off, 64);
  __shared__ float red[4];
  int lane = threadIdx.x & 63, wid = threadIdx.x >> 6;
  if (lane == 0) red[wid] = sq;
  __syncthreads();
  float tot = red[0] + red[1] + red[2] + red[3];
  float scale = g[h] / sqrtf(tot);
  w[h*D_ + d] = f2bf(x * scale);
}

// ---------------- transpose+convert both tensors: x [B][L][D] f32 -> xT [B][D][L] bf16
__global__ __launch_bounds__(256) void transpose_kernel(const float* __restrict__ a,
      const float* __restrict__ b, unsigned short* __restrict__ aT,
      unsigned short* __restrict__ bT){
  __shared__ float tile[32][33];
  int sel = blockIdx.z >> 3;
  int bz  = blockIdx.z & 7;
  const float* x = sel ? b : a;
  unsigned short* xT = sel ? bT : aT;
  int l0 = blockIdx.x * 32;
  int d0 = blockIdx.y * 32;
  int tx = threadIdx.x, ty = threadIdx.y; // (32,8)
  const float* xp = x + (size_t)bz * L_ * D_;
  for (int k = 0; k < 4; k++)
    tile[ty + 8*k][tx] = xp[(size_t)(l0 + ty + 8*k) * D_ + d0 + tx];
  __syncthreads();
  unsigned short* op = xT + (size_t)bz * D_ * L_;
  for (int k = 0; k < 4; k++)
    op[(size_t)(d0 + ty + 8*k) * L_ + l0 + tx] = f2bf(tile[tx][ty + 8*k]);
}

// ---------------- hx = bf16(scale * relu(x @ w^T + bias)); all 256 cols per block
__global__ __launch_bounds__(256) void hgemm_kernel(const float* __restrict__ a,
      const float* __restrict__ b, const unsigned short* __restrict__ wa,
      const unsigned short* __restrict__ wb, const float* __restrict__ a_bias,
      const float* __restrict__ b_bias, const float* __restrict__ tau_ptr,
      unsigned short* __restrict__ ha, unsigned short* __restrict__ hb){
  int sel = blockIdx.y;
  const float* x = sel ? b : a;
  const unsigned short* w = sel ? wb : wa;
  const float* bias = sel ? b_bias : a_bias;
  unsigned short* hx = sel ? hb : ha;
  float scale = sel ? 1.0f : tau_ptr[0];
  int m0 = blockIdx.x * 64;
  int lane = threadIdx.x & 63, wid = threadIdx.x >> 6;
  int p = lane & 15, q = lane >> 4;
  int row = m0 + wid*16 + p;
  f32x4 acc[16] = {};
  for (int kk = 0; kk < 8; kk++){
    const float* ap = x + (size_t)row * 256 + kk*32 + q*8;
    f32x4 a0 = *(const f32x4*)ap;
    f32x4 a1 = *(const f32x4*)(ap + 4);
    bf16x8 af;
    af[0]=(short)f2bf(a0[0]); af[1]=(short)f2bf(a0[1]); af[2]=(short)f2bf(a0[2]); af[3]=(short)f2bf(a0[3]);
    af[4]=(short)f2bf(a1[0]); af[5]=(short)f2bf(a1[1]); af[6]=(short)f2bf(a1[2]); af[7]=(short)f2bf(a1[3]);
    #pragma unroll
    for (int n = 0; n < 16; n++){
      bf16x8 bfr = *(const bf16x8*)(w + (size_t)(n*16 + p) * 256 + kk*32 + q*8);
      acc[n] = MFMA(af, bfr, acc[n]);
    }
  }
  #pragma unroll
  for (int n = 0; n < 16; n++){
    float bv = bias[n*16 + p];
    #pragma unroll
    for (int r = 0; r < 4; r++){
      int orow = m0 + wid*16 + q*4 + r;
      float vv = acc[n][r] + bv;
      vv = vv > 0.f ? vv : 0.f;
      hx[(size_t)orow * 256 + n*16 + p] = f2bf(vv * scale);
    }
  }
}

// ---------------- fused flash alignment, LDS-staged + double-buffered.
// 8 waves = 4 row-groups (wr: 32 rows) x 2 (wc). QK: wc splits the 64 j-cols
// (2 MFMAs per B-read). PV: wc splits D (acc[2][8] = 64 AGPR, no spill);
// W shared per wr-pair via WT; per-tile pair max-exchange keeps m_run
// identical in both waves. 3 barriers/tile; stage drains at bar1 after QK.
__global__ __launch_bounds__(512, 2) void flash_kernel(
    const unsigned short* __restrict__ ha, const unsigned short* __restrict__ hb,
    const unsigned short* __restrict__ aT, const unsigned short* __restrict__ bT,
    const int* __restrict__ mask_a, const int* __restrict__ mask_b,
    float* __restrict__ out)
{
  __shared__ __align__(16) unsigned short HBT[2][64][256];  // 64 KB
  __shared__ __align__(16) unsigned short VTL[2][256][64];  // 64 KB
  __shared__ __align__(16) unsigned short WT[4][32][72];    // 18 KB, row 144B (16B-mult)
  __shared__ float MST[8][32];
  __shared__ float SST[8][32];

  const int bid = blockIdx.x;
  const int s   = bid & 15;             // stream id; XCD = bid%8
  const int dir = s >> 3;
  const int bz  = s & 7;
  const int i0  = (bid >> 4) * BM;
  const int tid = threadIdx.x;
  const int lane = tid & 63;
  const int wid  = tid >> 6;
  const int wr = wid >> 1, wc = wid & 1;
  const int p = lane & 15, q = lane >> 4;

  const unsigned short* hA = dir ? hb : ha;
  const unsigned short* hB = dir ? ha : hb;
  const unsigned short* vT = dir ? aT : bT;
  const int* mask = dir ? mask_a : mask_b;
  float* outp = out + ((size_t)dir * B_ + bz) * L_ * D_;

  const unsigned short* hAp = hA + (size_t)bz * L_ * H_;
  const unsigned short* hBp = hB + (size_t)bz * L_ * H_;
  const unsigned short* vTp = vT + (size_t)bz * D_ * L_;
  const int* mp = mask + bz * L_;

  // staging source geometry (512 threads cooperatively stage 64KB/tile)
  const int hb_r0 = wid*2 + (lane >> 5);      // + k*16
  const int hb_s  = lane & 31;
  const int vt_r0 = wid*8 + (lane >> 3);      // + k*64
  const int vt_s  = lane & 7;

  // A fragments: this wave's 32 rows (two 16-row groups)
  bf16x8 af[2][8];
  #pragma unroll
  for (int g = 0; g < 2; ++g)
    #pragma unroll
    for (int kk = 0; kk < 8; ++kk)
      af[g][kk] = *(const bf16x8*)(hAp + (size_t)(i0 + wr*32 + g*16 + p) * H_ + kk*32 + q*8);

  f32x4 acc[2][8];
  #pragma unroll
  for (int g = 0; g < 2; ++g)
    #pragma unroll
    for (int n = 0; n < 8; ++n) acc[g][n] = (f32x4){0.f,0.f,0.f,0.f};
  float m_run[2][4], s_run[2][4];
  #pragma unroll
  for (int g = 0; g < 2; ++g)
    #pragma unroll
    for (int r = 0; r < 4; ++r){ m_run[g][r] = -1e30f; s_run[g][r] = 0.f; }

  #define STAGE(bb, jj0) do {                                                     \
    _Pragma("unroll")                                                             \
    for (int k = 0; k < 4; ++k){                                                  \
      int rr = k*16 + hb_r0;                                                      \
      int sp = hb_s ^ (rr & 7);                                                   \
      gload_lds16(hBp + (size_t)((jj0) + rr) * H_ + sp*8,                         \
                  &HBT[bb][0][0] + (k*8192 + wid*1024)/2);                        \
    }                                                                             \
    _Pragma("unroll")                                                             \
    for (int k = 0; k < 4; ++k){                                                  \
      int rr = k*64 + vt_r0;                                                      \
      int sp = vt_s ^ (rr & 7);                                                   \
      gload_lds16(vTp + (size_t)rr * L_ + (jj0) + sp*8,                           \
                  &VTL[bb][0][0] + (k*8192 + wid*1024)/2);                        \
    }                                                                             \
  } while(0)

  STAGE(0, 0);
  __syncthreads();

  for (int jt = 0; jt < NT; ++jt){
    const int j0 = jt * TJ;
    const int cur = jt & 1;
    if (jt + 1 < NT) STAGE(cur ^ 1, j0 + TJ);

    // mask terms for this wave's 2 col-groups (cols j0 + wc*32 + cg*16 + p)
    float mm[2];
    #pragma unroll
    for (int cg = 0; cg < 2; ++cg)
      mm[cg] = (mp[j0 + wc*32 + cg*16 + p] > 0) ? 0.f : -1e9f;

    // ---- QK: P[32 rows][32 cols] for this wave's j-half
    f32x4 accp[2][2];
    #pragma unroll
    for (int g = 0; g < 2; ++g)
      #pragma unroll
      for (int cg = 0; cg < 2; ++cg) accp[g][cg] = (f32x4){0.f,0.f,0.f,0.f};
    __builtin_amdgcn_s_setprio(1);
    #pragma unroll
    for (int kk = 0; kk < 8; ++kk){
      const int r0 = wc*32 + p;
      const int sp = ((kk*4 + q) ^ (p & 7)) * 8;
      bf16x8 b0 = *(const bf16x8*)(&HBT[cur][0][0] + r0*256 + sp);
      bf16x8 b1 = *(const bf16x8*)(&HBT[cur][0][0] + (r0+16)*256 + sp);
      accp[0][0] = MFMA(af[0][kk], b0, accp[0][0]);
      accp[1][0] = MFMA(af[1][kk], b0, accp[1][0]);
      accp[0][1] = MFMA(af[0][kk], b1, accp[0][1]);
      accp[1][1] = MFMA(af[1][kk], b1, accp[1][1]);
    }
    __builtin_amdgcn_s_setprio(0);

    // ---- mask + this wave's tile max
    float tmax[2][4];
    #pragma unroll
    for (int g = 0; g < 2; ++g)
      #pragma unroll
      for (int r = 0; r < 4; ++r){
        accp[g][0][r] += mm[0];
        accp[g][1][r] += mm[1];
        tmax[g][r] = fmaxf(accp[g][0][r], accp[g][1][r]);
      }
    #pragma unroll
    for (int off = 1; off < 16; off <<= 1)
      #pragma unroll
      for (int g = 0; g < 2; ++g)
        #pragma unroll
        for (int r = 0; r < 4; ++r)
          tmax[g][r] = fmaxf(tmax[g][r], __shfl_xor(tmax[g][r], off, 64));

    // publish wave max for pair exchange
    if (p == 0){
      #pragma unroll
      for (int g = 0; g < 2; ++g)
        #pragma unroll
        for (int r = 0; r < 4; ++r)
          MST[wid][g*16 + q*4 + r] = tmax[g][r];
    }
    __syncthreads();   // bar1: MST visible; stage drains here (overlapped QK)

    // ---- pair max; identical in both waves -> identical m_run evolution
    float pm[2][4];
    #pragma unroll
    for (int g = 0; g < 2; ++g)
      #pragma unroll
      for (int r = 0; r < 4; ++r)
        pm[g][r] = fmaxf(tmax[g][r], MST[wid ^ 1][g*16 + q*4 + r]);

    int need = 0;
    #pragma unroll
    for (int g = 0; g < 2; ++g)
      #pragma unroll
      for (int r = 0; r < 4; ++r)
        need |= (pm[g][r] > m_run[g][r] + 8.f) ? 1 : 0;
    if (__any(need)){
      float fsc[2][4];
      #pragma unroll
      for (int g = 0; g < 2; ++g)
        #pragma unroll
        for (int r = 0; r < 4; ++r){
          float mn = fmaxf(m_run[g][r], pm[g][r]);
          fsc[g][r] = __expf(m_run[g][r] - mn);
          s_run[g][r] *= fsc[g][r];
          m_run[g][r] = mn;
        }
      #pragma unroll
      for (int g = 0; g < 2; ++g)
        #pragma unroll
        for (int n = 0; n < 8; ++n)
          #pragma unroll
          for (int r = 0; r < 4; ++r)
            acc[g][n][r] *= fsc[g][r];
    }

    // ---- weights -> bf16 -> shared per-pair WT (this wave's 32-col half)
    #pragma unroll
    for (int g = 0; g < 2; ++g)
      #pragma unroll
      for (int cg = 0; cg < 2; ++cg)
        #pragma unroll
        for (int r = 0; r < 4; ++r){
          float w = __expf(accp[g][cg][r] - m_run[g][r]);
          s_run[g][r] += w;
          WT[wr][g*16 + q*4 + r][wc*32 + cg*16 + p] = f2bf(w);
        }
    __syncthreads();   // bar2: WT complete for both halves

    // ---- PV: acc += W[32 rows][64 j] @ V[64 j][this wave's 128 d-cols]
    bf16x8 wf[2][2];
    #pragma unroll
    for (int g = 0; g < 2; ++g)
      #pragma unroll
      for (int ks = 0; ks < 2; ++ks)
        wf[g][ks] = *(const bf16x8*)(&WT[wr][g*16 + p][ks*32 + q*8]);
    __builtin_amdgcn_s_setprio(1);
    #pragma unroll
    for (int n = 0; n < 8; ++n){
      const int d = wc*128 + n*16 + p;
      #pragma unroll
      for (int ks = 0; ks < 2; ++ks){
        const int sp = ((ks*4 + q) ^ (p & 7)) * 8;
        bf16x8 vf = *(const bf16x8*)(&VTL[cur][0][0] + d*64 + sp);
        acc[0][n] = MFMA(wf[0][ks], vf, acc[0][n]);
        acc[1][n] = MFMA(wf[1][ks], vf, acc[1][n]);
      }
    }
    __builtin_amdgcn_s_setprio(0);

    __syncthreads();   // bar3: PV done before next tile's STAGE/WT overwrite
  }
  #undef STAGE

  // ---- finish: reduce s over the 16 col-lanes, pair-sum, normalize, store
  #pragma unroll
  for (int off = 1; off < 16; off <<= 1)
    #pragma unroll
    for (int g = 0; g < 2; ++g)
      #pragma unroll
      for (int r = 0; r < 4; ++r)
        s_run[g][r] += __shfl_xor(s_run[g][r], off, 64);
  if (p == 0){
    #pragma unroll
    for (int g = 0; g < 2; ++g)
      #pragma unroll
      for (int r = 0; r < 4; ++r)
        SST[wid][g*16 + q*4 + r] = s_run[g][r];
  }
  __syncthreads();
  float invS[2][4];
  #pragma unroll
  for (int g = 0; g < 2; ++g)
    #pragma unroll
    for (int r = 0; r < 4; ++r)
      invS[g][r] = 1.0f / (s_run[g][r] + SST[wid ^ 1][g*16 + q*4 + r]);

  #pragma unroll
  for (int g = 0; g < 2; ++g)
    #pragma unroll
    for (int n = 0; n < 8; ++n)
      #pragma unroll
      for (int r = 0; r < 4; ++r){
        int row = i0 + wr*32 + g*16 + q*4 + r;
        outp[(size_t)row * D_ + wc*128 + n*16 + p] = acc[g][n][r] * invS[g][r];
      }
}

extern "C" void kernel_launch(void* const* d_in, const int* in_sizes, int n_in,
                              void* d_out, int out_size, void* d_ws, size_t ws_size,
                              hipStream_t stream) {
  const float* a      = (const float*)d_in[0];
  const float* b      = (const float*)d_in[1];
  const int*   mask_a = (const int*)d_in[2];
  const int*   mask_b = (const int*)d_in[3];
  const float* a_v    = (const float*)d_in[4];
  const float* a_g    = (const float*)d_in[5];
  const float* a_bias = (const float*)d_in[6];
  const float* b_v    = (const float*)d_in[7];
  const float* b_g    = (const float*)d_in[8];
  const float* b_bias = (const float*)d_in[9];
  const float* tau    = (const float*)d_in[10];

  float* out = (float*)d_out;

  char* ws = (char*)d_ws;
  const size_t SZ_W  = (size_t)H_ * D_ * 2;        // 128 KB
  const size_t SZ_H  = (size_t)B_ * L_ * H_ * 2;   // 8 MB
  unsigned short* wa = (unsigned short*)(ws);
  unsigned short* wb = (unsigned short*)(ws + SZ_W);
  unsigned short* ha = (unsigned short*)(ws + 2*SZ_W);
  unsigned short* hb = (unsigned short*)(ws + 2*SZ_W + SZ_H);
  unsigned short* aT = (unsigned short*)(ws + 2*SZ_W + 2*SZ_H);
  unsigned short* bT = (unsigned short*)(ws + 2*SZ_W + 3*SZ_H);
  size_t need = 2*SZ_W + 4*SZ_H;
  if (ws_size < need) return;

  // 1. normalized weights (both, one launch)
  wnorm_kernel<<<dim3(H_, 2), 256, 0, stream>>>(a_v, a_g, b_v, b_g, wa, wb);

  // 2. transposed bf16 copies of a and b ([B][D][L], one launch)
  {
    dim3 g(L_/32, D_/32, 16), blk(32, 8);
    transpose_kernel<<<g, blk, 0, stream>>>(a, b, aT, bT);
  }

  // 3. ha = bf16(tau*relu(a@wa^T + bias)), hb = bf16(relu(b@wb^T + bias)) (one launch)
  {
    dim3 g((B_*L_)/64, 2);
    hgemm_kernel<<<g, 256, 0, stream>>>(a, b, wa, wb, a_bias, b_bias, tau, ha, hb);
  }

  // 4. fused flash alignment, both directions (256 blocks = 1/CU, XCD-affine)
  {
    flash_kernel<<<dim3((L_/BM) * B_ * 2), 512, 0, stream>>>(
        ha, hb, aT, bT, mask_a, mask_b, out);
  }
}

// Round 7
// 163.624 us; speedup vs baseline: 1.2783x; 1.0938x over previous
//
#include <hip/hip_runtime.h>
#include <hip/hip_bf16.h>
#include <stdint.h>

#define B_   8
#define L_   2048
#define D_   256
#define H_   256
#define TJ   64          // j-tile
#define NT   (L_/TJ)     // 32 tiles
#define BM   64          // rows per flash block
#define LOG2E 1.4426950408889634f

typedef short bf16x8 __attribute__((ext_vector_type(8)));
typedef short bf16x4 __attribute__((ext_vector_type(4)));
typedef float f32x4  __attribute__((ext_vector_type(4)));

#define MFMA(a,b,c) __builtin_amdgcn_mfma_f32_16x16x32_bf16(a,b,c,0,0,0)
#define EX2(x) __builtin_amdgcn_exp2f(x)

typedef unsigned int u32;
__device__ __forceinline__ void gload_lds16(const void* g, void* l){
  __builtin_amdgcn_global_load_lds((const __attribute__((address_space(1))) u32*)g,
                                   (__attribute__((address_space(3))) u32*)l, 16, 0, 0);
}

__device__ __forceinline__ unsigned short f2bf(float f){
  __hip_bfloat16 h = __float2bfloat16(f);
  unsigned short us;
  __builtin_memcpy(&us, &h, 2);
  return us;
}

// ---------------- weight norm (both sets in one launch; y selects a/b)
__global__ __launch_bounds__(256) void wnorm_kernel(const float* __restrict__ av,
      const float* __restrict__ ag, const float* __restrict__ bv,
      const float* __restrict__ bg, unsigned short* __restrict__ wa,
      unsigned short* __restrict__ wb){
  int sel = blockIdx.y;
  const float* v = sel ? bv : av;
  const float* g = sel ? bg : ag;
  unsigned short* w = sel ? wb : wa;
  int h = blockIdx.x;
  int d = threadIdx.x;
  float x = v[h*D_ + d];
  float sq = x*x;
  for (int off = 32; off; off >>= 1) sq += __shfl_down(sq, off, 64);
  __shared__ float red[4];
  int lane = threadIdx.x & 63, wid = threadIdx.x >> 6;
  if (lane == 0) red[wid] = sq;
  __syncthreads();
  float tot = red[0] + red[1] + red[2] + red[3];
  float scale = g[h] / sqrtf(tot);
  w[h*D_ + d] = f2bf(x * scale);
}

// ---------------- hx = bf16(scale * relu(x @ w^T + bias)), 64 rows x 256 cols,
// PLUS writes the transposed bf16 stripe xT[d][l0..l0+64) via LDS (kills the
// separate transpose kernel and its 64MB re-read). ha carries tau*log2e so the
// flash softmax runs in exp2 domain.
__global__ __launch_bounds__(256) void hgemm_kernel(const float* __restrict__ a,
      const float* __restrict__ b, const unsigned short* __restrict__ wa,
      const unsigned short* __restrict__ wb, const float* __restrict__ a_bias,
      const float* __restrict__ b_bias, const float* __restrict__ tau_ptr,
      unsigned short* __restrict__ ha, unsigned short* __restrict__ hb,
      unsigned short* __restrict__ aT, unsigned short* __restrict__ bT){
  __shared__ __align__(16) unsigned short xtile[256*68];  // [256 d][68 l-pad]
  int sel = blockIdx.y;
  const float* x = sel ? b : a;
  const unsigned short* w = sel ? wb : wa;
  const float* bias = sel ? b_bias : a_bias;
  unsigned short* hx = sel ? hb : ha;
  unsigned short* xT = sel ? bT : aT;
  float scale = sel ? 1.0f : tau_ptr[0] * LOG2E;
  int m0 = blockIdx.x * 64;
  int bz = m0 / L_, l0 = m0 % L_;
  int tid = threadIdx.x;
  int lane = tid & 63, wid = tid >> 6;
  int p = lane & 15, q = lane >> 4;
  int row = m0 + wid*16 + p;
  unsigned short* xtw = xtile + (q*8)*68 + (wid*16 + p);
  f32x4 acc[16] = {};
  for (int kk = 0; kk < 8; kk++){
    const float* ap = x + (size_t)row * 256 + kk*32 + q*8;
    f32x4 a0 = *(const f32x4*)ap;
    f32x4 a1 = *(const f32x4*)(ap + 4);
    bf16x8 af;
    af[0]=(short)f2bf(a0[0]); af[1]=(short)f2bf(a0[1]); af[2]=(short)f2bf(a0[2]); af[3]=(short)f2bf(a0[3]);
    af[4]=(short)f2bf(a1[0]); af[5]=(short)f2bf(a1[1]); af[6]=(short)f2bf(a1[2]); af[7]=(short)f2bf(a1[3]);
    #pragma unroll
    for (int e = 0; e < 8; e++)
      xtw[(kk*32 + e)*68] = (unsigned short)af[e];
    #pragma unroll
    for (int n = 0; n < 16; n++){
      bf16x8 bfr = *(const bf16x8*)(w + (size_t)(n*16 + p) * 256 + kk*32 + q*8);
      acc[n] = MFMA(af, bfr, acc[n]);
    }
  }
  #pragma unroll
  for (int n = 0; n < 16; n++){
    float bv = bias[n*16 + p];
    #pragma unroll
    for (int r = 0; r < 4; r++){
      int orow = m0 + wid*16 + q*4 + r;
      float vv = acc[n][r] + bv;
      vv = vv > 0.f ? vv : 0.f;
      hx[(size_t)orow * 256 + n*16 + p] = f2bf(vv * scale);
    }
  }
  __syncthreads();
  // coalesced xT writeout: 16 iters, 16 rows/iter, b64 chunks (8B-aligned in LDS)
  #pragma unroll
  for (int it = 0; it < 16; it++){
    int d = it*16 + (tid >> 4);
    int c = (tid & 15) * 4;
    bf16x4 v = *(const bf16x4*)(&xtile[d*68 + c]);
    *(bf16x4*)(xT + ((size_t)bz*D_ + d)*L_ + l0 + c) = v;
  }
}

// ---------------- fused flash alignment. 256 threads (4 waves), 64 rows/block,
// 2 blocks/CU (two independent barrier groups hide each other's stalls).
// Single-buffered TJ=64 staging via global_load_lds (drained by barA).
// 4 waves = 2 row-groups (wr: 32 rows) x 2 (wc). QK: wc splits j-cols.
// PV: wc splits D (acc[2][8]); WT shared per wr-pair, XOR-swizzled slots.
// Softmax in exp2 domain (ha pre-scaled by log2e).
__global__ __launch_bounds__(256, 2) void flash_kernel(
    const unsigned short* __restrict__ ha, const unsigned short* __restrict__ hb,
    const unsigned short* __restrict__ aT, const unsigned short* __restrict__ bT,
    const int* __restrict__ mask_a, const int* __restrict__ mask_b,
    float* __restrict__ out)
{
  __shared__ __align__(16) unsigned short HBT[64][256];   // 32 KB
  __shared__ __align__(16) unsigned short VTL[256][64];   // 32 KB
  __shared__ __align__(16) unsigned short WT[2][32][64];  // 8 KB (slot ^= row&7)
  __shared__ float MST[4][32];
  __shared__ float SST[4][32];

  const int bid = blockIdx.x;
  const int s   = bid & 15;             // stream; XCD = bid%8 = bz
  const int dir = s >> 3;
  const int bz  = s & 7;
  const int i0  = (bid >> 4) * BM;
  const int tid = threadIdx.x;
  const int lane = tid & 63;
  const int wid  = tid >> 6;            // 0..3
  const int wr = wid >> 1, wc = wid & 1;
  const int p = lane & 15, q = lane >> 4;

  const unsigned short* hA = dir ? hb : ha;
  const unsigned short* hB = dir ? ha : hb;
  const unsigned short* vT = dir ? aT : bT;
  const int* mask = dir ? mask_a : mask_b;
  float* outp = out + ((size_t)dir * B_ + bz) * L_ * D_;

  const unsigned short* hAp = hA + (size_t)bz * L_ * H_;
  const unsigned short* hBp = hB + (size_t)bz * L_ * H_;
  const unsigned short* vTp = vT + (size_t)bz * D_ * L_;
  const int* mp = mask + bz * L_;

  // staging geometry: 256 threads x 8 loads per 32KB buffer
  const int hb_r0 = tid >> 5;           // + k*8
  const int hb_s  = tid & 31;
  const int vt_r0 = tid >> 3;           // + k*32
  const int vt_s  = tid & 7;

  // A fragments: this wave's 32 rows (two 16-row groups)
  bf16x8 af[2][8];
  #pragma unroll
  for (int g = 0; g < 2; ++g)
    #pragma unroll
    for (int kk = 0; kk < 8; ++kk)
      af[g][kk] = *(const bf16x8*)(hAp + (size_t)(i0 + wr*32 + g*16 + p) * H_ + kk*32 + q*8);

  f32x4 acc[2][8];
  #pragma unroll
  for (int g = 0; g < 2; ++g)
    #pragma unroll
    for (int n = 0; n < 8; ++n) acc[g][n] = (f32x4){0.f,0.f,0.f,0.f};
  float m_run[2][4], s_run[2][4];
  #pragma unroll
  for (int g = 0; g < 2; ++g)
    #pragma unroll
    for (int r = 0; r < 4; ++r){ m_run[g][r] = -1e30f; s_run[g][r] = 0.f; }

  #define STAGE(jj0) do {                                                         \
    _Pragma("unroll")                                                             \
    for (int k = 0; k < 8; ++k){                                                  \
      int rr = k*8 + hb_r0;                                                       \
      int sp = hb_s ^ (rr & 7);                                                   \
      gload_lds16(hBp + (size_t)((jj0) + rr) * H_ + sp*8,                         \
                  &HBT[0][0] + k*2048 + tid*8);                                   \
    }                                                                             \
    _Pragma("unroll")                                                             \
    for (int k = 0; k < 8; ++k){                                                  \
      int rr = k*32 + vt_r0;                                                      \
      int sp = vt_s ^ (rr & 7);                                                   \
      gload_lds16(vTp + (size_t)rr * L_ + (jj0) + sp*8,                           \
                  &VTL[0][0] + k*2048 + tid*8);                                   \
    }                                                                             \
  } while(0)

  for (int jt = 0; jt < NT; ++jt){
    const int j0 = jt * TJ;
    STAGE(j0);
    float mm[2];
    #pragma unroll
    for (int cg = 0; cg < 2; ++cg)
      mm[cg] = (mp[j0 + wc*32 + cg*16 + p] > 0) ? 0.f : -1e9f;
    __syncthreads();   // barA: staging drained (compiler emits vmcnt(0))

    // ---- QK: P[32 rows][32 cols] for this wave's j-half (exp2-domain scores)
    f32x4 accp[2][2];
    #pragma unroll
    for (int g = 0; g < 2; ++g)
      #pragma unroll
      for (int cg = 0; cg < 2; ++cg) accp[g][cg] = (f32x4){0.f,0.f,0.f,0.f};
    __builtin_amdgcn_s_setprio(1);
    #pragma unroll
    for (int kk = 0; kk < 8; ++kk){
      const int r0 = wc*32 + p;
      const int sp = ((kk*4 + q) ^ (p & 7)) * 8;
      bf16x8 b0 = *(const bf16x8*)(&HBT[0][0] + r0*256 + sp);
      bf16x8 b1 = *(const bf16x8*)(&HBT[0][0] + (r0+16)*256 + sp);
      accp[0][0] = MFMA(af[0][kk], b0, accp[0][0]);
      accp[1][0] = MFMA(af[1][kk], b0, accp[1][0]);
      accp[0][1] = MFMA(af[0][kk], b1, accp[0][1]);
      accp[1][1] = MFMA(af[1][kk], b1, accp[1][1]);
    }
    __builtin_amdgcn_s_setprio(0);

    // ---- mask + this wave's tile max
    float tmax[2][4];
    #pragma unroll
    for (int g = 0; g < 2; ++g)
      #pragma unroll
      for (int r = 0; r < 4; ++r){
        accp[g][0][r] += mm[0];
        accp[g][1][r] += mm[1];
        tmax[g][r] = fmaxf(accp[g][0][r], accp[g][1][r]);
      }
    #pragma unroll
    for (int off = 1; off < 16; off <<= 1)
      #pragma unroll
      for (int g = 0; g < 2; ++g)
        #pragma unroll
        for (int r = 0; r < 4; ++r)
          tmax[g][r] = fmaxf(tmax[g][r], __shfl_xor(tmax[g][r], off, 64));

    if (p == 0){
      #pragma unroll
      for (int g = 0; g < 2; ++g)
        #pragma unroll
        for (int r = 0; r < 4; ++r)
          MST[wid][g*16 + q*4 + r] = tmax[g][r];
    }
    __syncthreads();   // barB: MST visible

    // ---- pair max; identical in both waves -> identical m_run evolution
    float pm[2][4];
    #pragma unroll
    for (int g = 0; g < 2; ++g)
      #pragma unroll
      for (int r = 0; r < 4; ++r)
        pm[g][r] = fmaxf(tmax[g][r], MST[wid ^ 1][g*16 + q*4 + r]);

    int need = 0;
    #pragma unroll
    for (int g = 0; g < 2; ++g)
      #pragma unroll
      for (int r = 0; r < 4; ++r)
        need |= (pm[g][r] > m_run[g][r] + 11.54f) ? 1 : 0;
    if (__any(need)){
      float fsc[2][4];
      #pragma unroll
      for (int g = 0; g < 2; ++g)
        #pragma unroll
        for (int r = 0; r < 4; ++r){
          float mn = fmaxf(m_run[g][r], pm[g][r]);
          fsc[g][r] = EX2(m_run[g][r] - mn);
          s_run[g][r] *= fsc[g][r];
          m_run[g][r] = mn;
        }
      #pragma unroll
      for (int g = 0; g < 2; ++g)
        #pragma unroll
        for (int n = 0; n < 8; ++n)
          #pragma unroll
          for (int r = 0; r < 4; ++r)
            acc[g][n][r] *= fsc[g][r];
    }

    // ---- weights -> bf16 -> WT (shared per wr-pair; 16B slot ^= row&7)
    #pragma unroll
    for (int g = 0; g < 2; ++g)
      #pragma unroll
      for (int cg = 0; cg < 2; ++cg)
        #pragma unroll
        for (int r = 0; r < 4; ++r){
          float w = EX2(accp[g][cg][r] - m_run[g][r]);
          s_run[g][r] += w;
          int slot = (wc*4 + cg*2 + (p>>3)) ^ ((q*4 + r) & 7);
          WT[wr][g*16 + q*4 + r][slot*8 + (p & 7)] = f2bf(w);
        }
    __syncthreads();   // barC: WT complete for both halves

    bf16x8 wf[2][2];
    #pragma unroll
    for (int g = 0; g < 2; ++g)
      #pragma unroll
      for (int ks = 0; ks < 2; ++ks)
        wf[g][ks] = *(const bf16x8*)(&WT[wr][g*16 + p][(((ks*4 + q) ^ (p & 7)))*8]);

    // ---- PV: acc += W[32 rows][64 j] @ V[64 j][this wave's 128 d-cols]
    __builtin_amdgcn_s_setprio(1);
    #pragma unroll
    for (int n = 0; n < 8; ++n){
      const int d = wc*128 + n*16 + p;
      #pragma unroll
      for (int ks = 0; ks < 2; ++ks){
        const int sp = ((ks*4 + q) ^ (p & 7)) * 8;
        bf16x8 vf = *(const bf16x8*)(&VTL[0][0] + d*64 + sp);
        acc[0][n] = MFMA(wf[0][ks], vf, acc[0][n]);
        acc[1][n] = MFMA(wf[1][ks], vf, acc[1][n]);
      }
    }
    __builtin_amdgcn_s_setprio(0);

    __syncthreads();   // barD: all reads done; next STAGE may overwrite
  }
  #undef STAGE

  // ---- finish: reduce s over the 16 col-lanes, pair-sum, normalize, store
  #pragma unroll
  for (int off = 1; off < 16; off <<= 1)
    #pragma unroll
    for (int g = 0; g < 2; ++g)
      #pragma unroll
      for (int r = 0; r < 4; ++r)
        s_run[g][r] += __shfl_xor(s_run[g][r], off, 64);
  if (p == 0){
    #pragma unroll
    for (int g = 0; g < 2; ++g)
      #pragma unroll
      for (int r = 0; r < 4; ++r)
        SST[wid][g*16 + q*4 + r] = s_run[g][r];
  }
  __syncthreads();
  float invS[2][4];
  #pragma unroll
  for (int g = 0; g < 2; ++g)
    #pragma unroll
    for (int r = 0; r < 4; ++r)
      invS[g][r] = 1.0f / (s_run[g][r] + SST[wid ^ 1][g*16 + q*4 + r]);

  #pragma unroll
  for (int g = 0; g < 2; ++g)
    #pragma unroll
    for (int n = 0; n < 8; ++n)
      #pragma unroll
      for (int r = 0; r < 4; ++r){
        int row = i0 + wr*32 + g*16 + q*4 + r;
        outp[(size_t)row * D_ + wc*128 + n*16 + p] = acc[g][n][r] * invS[g][r];
      }
}

extern "C" void kernel_launch(void* const* d_in, const int* in_sizes, int n_in,
                              void* d_out, int out_size, void* d_ws, size_t ws_size,
                              hipStream_t stream) {
  const float* a      = (const float*)d_in[0];
  const float* b      = (const float*)d_in[1];
  const int*   mask_a = (const int*)d_in[2];
  const int*   mask_b = (const int*)d_in[3];
  const float* a_v    = (const float*)d_in[4];
  const float* a_g    = (const float*)d_in[5];
  const float* a_bias = (const float*)d_in[6];
  const float* b_v    = (const float*)d_in[7];
  const float* b_g    = (const float*)d_in[8];
  const float* b_bias = (const float*)d_in[9];
  const float* tau    = (const float*)d_in[10];

  float* out = (float*)d_out;

  char* ws = (char*)d_ws;
  const size_t SZ_W  = (size_t)H_ * D_ * 2;        // 128 KB
  const size_t SZ_H  = (size_t)B_ * L_ * H_ * 2;   // 8 MB
  unsigned short* wa = (unsigned short*)(ws);
  unsigned short* wb = (unsigned short*)(ws + SZ_W);
  unsigned short* ha = (unsigned short*)(ws + 2*SZ_W);
  unsigned short* hb = (unsigned short*)(ws + 2*SZ_W + SZ_H);
  unsigned short* aT = (unsigned short*)(ws + 2*SZ_W + 2*SZ_H);
  unsigned short* bT = (unsigned short*)(ws + 2*SZ_W + 3*SZ_H);
  size_t need = 2*SZ_W + 4*SZ_H;
  if (ws_size < need) return;

  // 1. normalized weights (both, one launch)
  wnorm_kernel<<<dim3(H_, 2), 256, 0, stream>>>(a_v, a_g, b_v, b_g, wa, wb);

  // 2. h = bf16(scale*relu(x@w^T+bias)) AND transposed bf16 copies (one launch)
  {
    dim3 g((B_*L_)/64, 2);
    hgemm_kernel<<<g, 256, 0, stream>>>(a, b, wa, wb, a_bias, b_bias, tau,
                                        ha, hb, aT, bT);
  }

  // 3. fused flash alignment, both directions (512 blocks = 2/CU, XCD-affine)
  {
    flash_kernel<<<dim3((L_/BM) * B_ * 2), 256, 0, stream>>>(
        ha, hb, aT, bT, mask_a, mask_b, out);
  }
}